// Round 5
// baseline (395.665 us; speedup 1.0000x reference)
//
#include <hip/hip_runtime.h>

typedef __attribute__((ext_vector_type(8)))  short short8;   // 8 bf16 (4 VGPRs)
typedef __attribute__((ext_vector_type(16))) float f32x16;   // 32x32 MFMA acc
typedef unsigned short ushort_t;
typedef unsigned int uint32;
typedef unsigned long long uint64;

#define NROWS 8192
#define NCODE 8192
#define DIM   512

// ---------------- d_out layout (floats) ----------------
#define OUT_Q      0
#define OUT_LOSS   4194304
#define OUT_IDX    4194305
#define OUT_MIND   4202497
#define OUT_COMMIT 4210689

// ---------------- ws layout (floats) ----------------
// Same 17.4 MB footprint as previous rounds (minmat replaces the dead blo).
#define WS_ENORM  0           // 8192 floats
#define WS_XNORM  8192        // 8192 floats
#define WS_ENMAX  16384       // 1 float
#define WS_LPART  147456      // 2048 floats
#define WS_BHI    150528      // 4,194,304 ushorts (8.39 MB)
#define WS_MINMAT 2247680     // 8192*1024 u16 (8.39 MB)

// ===========================================================================
__device__ inline uint32 bf16_rne(float f) {
    uint32 u = __float_as_uint(f);
    return (u + 0x7FFFu + ((u >> 16) & 1u)) >> 16;
}

__device__ inline void gload16(const ushort_t* g, ushort_t* l) {
    __builtin_amdgcn_global_load_lds(
        (const __attribute__((address_space(1))) void*)g,
        (__attribute__((address_space(3))) void*)l, 16, 0, 0);
}

// ===========================================================================
// Kernel 1: convert x and codebook to fragment-ordered bf16 HI tiles only.
// Tile = 128 rows x 32 k, 8 KB, 8 chunks of 1 KB: chunk c = r32*2 + k16;
// lane L holds row = r32*32 + (L&31), k = k16*16 + (L>>5)*8 + j.
// Also writes exact fp32 row norms (xnorm for inputs, enorm for codebook).
__global__ __launch_bounds__(256) void conv_kernel(const float* __restrict__ x,
                                                   const float* __restrict__ cb,
                                                   ushort_t* __restrict__ ahi,
                                                   ushort_t* __restrict__ bhi,
                                                   float* __restrict__ xnorm,
                                                   float* __restrict__ enorm) {
    int gid  = blockIdx.x * 256 + threadIdx.x;   // 0..1048575
    bool isA = gid < 524288;
    int g    = isA ? gid : gid - 524288;
    int row  = g >> 6;
    int lane = g & 63;
    int k0   = lane * 8;
    const float* src = (isA ? x : cb) + (size_t)row * DIM + k0;
    float v[8];
    *(float4*)&v[0] = *(const float4*)src;
    *(float4*)&v[4] = *(const float4*)(src + 4);
    float s = 0.0f;
    uint32 h[8];
    #pragma unroll
    for (int i = 0; i < 8; ++i) {
        s += v[i] * v[i];
        h[i] = bf16_rne(v[i]);
    }
    int tile = (row >> 7) * 16 + (k0 >> 5);
    int rp = row & 127, kp = k0 & 31;
    int c  = (rp >> 5) * 2 + (kp >> 4);
    int L  = (rp & 31) + (((kp >> 3) & 1) << 5);
    size_t off = (size_t)tile * 4096 + c * 512 + L * 8;   // ushort units
    uint4 ph;
    ph.x = h[0] | (h[1] << 16); ph.y = h[2] | (h[3] << 16);
    ph.z = h[4] | (h[5] << 16); ph.w = h[6] | (h[7] << 16);
    if (isA) *(uint4*)(ahi + off) = ph;
    else     *(uint4*)(bhi + off) = ph;
    #pragma unroll
    for (int o = 32; o > 0; o >>= 1) s += __shfl_down(s, o);
    if (lane == 0) { if (isA) xnorm[row] = s; else enorm[row] = s; }
}

// ===========================================================================
// Kernel 1b: en_max = max over codebook norms (needed for the prune bound).
__global__ __launch_bounds__(256) void prep_kernel(const float* __restrict__ enorm,
                                                   float* __restrict__ enmax) {
    __shared__ float sm[256];
    float m = 0.0f;
    for (int i = threadIdx.x; i < NCODE; i += 256) m = fmaxf(m, enorm[i]);
    sm[threadIdx.x] = m;
    __syncthreads();
    #pragma unroll
    for (int o = 128; o > 0; o >>= 1) {
        if (threadIdx.x < o) sm[threadIdx.x] = fmaxf(sm[threadIdx.x], sm[threadIdx.x + o]);
        __syncthreads();
    }
    if (threadIdx.x == 0) enmax[0] = sm[0];
}

// ===========================================================================
// Kernel 2 (R5): hi-only approximate distance GEMM -> per-8-col-subtile min.
// 1/3 of the previous MFMA work (hh term only); exactness restored by the
// refine kernel using the bound |d - d~| <= 2*2.02*2^-8*sqrt(xn*en_max).
// Structure = R0's proven 2-buffer schedule. Block 128 rows x 256 cols,
// 4 waves (2x2), wave tile 64x128 = acc[2][4]. K swept fully (32 k16 steps),
// single epilogue. d~ quantized: q = (en - 2*dot + 1536) * 16 as u16.
// Grid 2048 = 64 bx x 32 by; XCD q&7 owns an 8-bx band (A slice L2-resident).
__global__ __launch_bounds__(256, 2) void vq_mfma_kernel(
        const ushort_t* __restrict__ ahi, const ushort_t* __restrict__ bhi,
        const float* __restrict__ enorm, ushort_t* __restrict__ minmat) {
    __shared__ __align__(16) ushort_t smem[12288];   // 2 x 12 KB buffers

    const int tid  = threadIdx.x;            // 0..255
    const int wave = tid >> 6, lane = tid & 63;
    const int l31  = lane & 31, half = lane >> 5;
    const int q  = blockIdx.x;
    const int bx = (q & 7) * 8 + (q >> 8);   // 0..63 (128-row block)
    const int by = (q >> 3) & 31;            // 0..31 (256-col slice)
    const int wr = wave >> 1;                // 0..1 (64-row group)
    const int wc = wave & 1;                 // 0..1 (128-col group)

    f32x16 acc[2][4];
    #pragma unroll
    for (int i = 0; i < 2; ++i)
        #pragma unroll
        for (int j = 0; j < 4; ++j)
            #pragma unroll
            for (int r = 0; r < 16; ++r) acc[i][j][r] = 0.0f;

    // stage k16-step n into buffer n&1: A 4 KB + B 8 KB (3 gloads/thread)
    auto stage = [&](int n) {
        const int kc = n >> 1, k16 = n & 1;
        ushort_t* S = smem + (n & 1) * 6144;
        const int lo = (tid >> 6) * 1024 + (k16 << 9) + (tid & 63) * 8;
        gload16(ahi + (((size_t)(bx * 16 + kc)) << 12) + lo, S + tid * 8);
        gload16(bhi + (((size_t)((by * 2)     * 16 + kc)) << 12) + lo, S + 2048 + tid * 8);
        gload16(bhi + (((size_t)((by * 2 + 1) * 16 + kc)) << 12) + lo, S + 4096 + tid * 8);
    };

    stage(0);
    #pragma unroll 2
    for (int n = 0; n < 32; ++n) {
        __syncthreads();                 // drains stage(n)
        if (n < 31) stage(n + 1);        // async into other buffer
        const ushort_t* S = smem + (n & 1) * 6144;
        short8 ah[2], bh[4];
        #pragma unroll
        for (int ti = 0; ti < 2; ++ti)
            ah[ti] = *(const short8*)&S[(wr * 2 + ti) * 512 + lane * 8];
        #pragma unroll
        for (int tj = 0; tj < 4; ++tj)
            bh[tj] = *(const short8*)&S[2048 + (wc * 4 + tj) * 512 + lane * 8];
        __builtin_amdgcn_s_setprio(1);
        #pragma unroll
        for (int ti = 0; ti < 2; ++ti)
            #pragma unroll
            for (int tj = 0; tj < 4; ++tj)
                acc[ti][tj] = __builtin_amdgcn_mfma_f32_32x32x16_bf16(
                    ah[ti], bh[tj], acc[ti][tj], 0, 0, 0);
        __builtin_amdgcn_s_setprio(0);
    }

    // epilogue: q~ = (en - 2*dot + 1536)*16, min over 8-col groups -> minmat
    const int colbase = by * 256 + wc * 128;
    #pragma unroll
    for (int tj = 0; tj < 4; ++tj) {
        const int ci = colbase + tj * 32 + l31;
        const float en = enorm[ci];
        #pragma unroll
        for (int ti = 0; ti < 2; ++ti)
            #pragma unroll
            for (int r = 0; r < 16; ++r) {
                float d  = en - 2.0f * acc[ti][tj][r];
                float qf = fminf(fmaxf((d + 1536.0f) * 16.0f, 0.0f), 65535.0f);
                qf = fminf(qf, __shfl_xor(qf, 1));
                qf = fminf(qf, __shfl_xor(qf, 2));
                qf = fminf(qf, __shfl_xor(qf, 4));
                if ((l31 & 7) == 0) {
                    int row = bx * 128 + wr * 64 + ti * 32
                            + (r & 3) + 8 * (r >> 2) + 4 * half;
                    int sub = (colbase >> 3) + tj * 4 + (l31 >> 3);
                    minmat[(size_t)row * 1024 + sub] =
                        (ushort_t)__float2uint_rn(qf);
                }
            }
    }
}

// ===========================================================================
// Kernel 3 (R5): per-row scan of the 1024 subtile mins, exact fp32 refine of
// all columns in subtiles within the error window, then the finish work
// (idx, quantized gather, min_distance, loss partial). One wave per row.
__global__ __launch_bounds__(256) void refine_kernel(
        const float* __restrict__ x, const float* __restrict__ cb,
        const float* __restrict__ xnorm, const float* __restrict__ enorm,
        const float* __restrict__ enmax, const ushort_t* __restrict__ minmat,
        float* __restrict__ out_idx, float* __restrict__ qout,
        float* __restrict__ out_mind, float* __restrict__ lpart) {
    __shared__ float sred[4];
    const int wave = threadIdx.x >> 6, lane = threadIdx.x & 63;
    const int row  = blockIdx.x * 4 + wave;

    // ---- 1. load this row's 1024 u16 subtile mins (16 per lane) ----
    const ushort_t* mrow = minmat + (size_t)row * 1024;
    uint4 a0 = ((const uint4*)mrow)[lane * 2];
    uint4 a1 = ((const uint4*)mrow)[lane * 2 + 1];
    uint32 w[8] = {a0.x, a0.y, a0.z, a0.w, a1.x, a1.y, a1.z, a1.w};
    uint32 mn = 0xFFFFu;
    #pragma unroll
    for (int i = 0; i < 8; ++i)
        mn = min(mn, min(w[i] & 0xFFFFu, w[i] >> 16));
    #pragma unroll
    for (int o = 1; o < 64; o <<= 1) mn = min(mn, __shfl_xor(mn, o));

    // ---- 2. error window: |d - d~| <= 2*2.02*2^-8*sqrt(xn*en_max) ----
    const float xn = xnorm[row];
    const float T  = 0.0160f * sqrtf(xn * enmax[0]) + 0.2f;
    const uint32 thr = mn + (uint32)(32.0f * T) + 3u;   // 2T in q units + guards

    // ---- 3. exact fp32 evaluation of candidate subtiles ----
    float bestd = 3.4e38f;
    int   besti = 0x7FFFFFFF;
    const float* xr = x + (size_t)row * DIM;
    #pragma unroll
    for (int t = 0; t < 16; ++t) {
        uint32 qv = (t & 1) ? (w[t >> 1] >> 16) : (w[t >> 1] & 0xFFFFu);
        uint64 mask = __ballot(qv <= thr);
        while (mask) {
            int L = __builtin_ctzll(mask); mask &= mask - 1;
            int sub = L * 16 + t;                 // subtile 0..1023
            int c   = sub * 8 + (lane >> 3);      // this lane-group's col
            int ks  = lane & 7;                   // 64-dim k slice
            const float4* e4 = (const float4*)(cb + (size_t)c * DIM) + ks * 16;
            const float4* x4 = (const float4*)xr + ks * 16;
            float dot = 0.0f;
            #pragma unroll
            for (int u = 0; u < 16; ++u) {
                float4 e = e4[u]; float4 xv = x4[u];
                dot += xv.x * e.x + xv.y * e.y + xv.z * e.z + xv.w * e.w;
            }
            dot += __shfl_xor(dot, 1);
            dot += __shfl_xor(dot, 2);
            dot += __shfl_xor(dot, 4);            // all 8 lanes: full dot
            float d = xn + enorm[c] - 2.0f * dot;
            #pragma unroll
            for (int o = 8; o < 64; o <<= 1) {    // merge 8 col-groups
                float d2 = __shfl_xor(d, o);
                int   c2 = __shfl_xor(c, o);
                if (d2 < d || (d2 == d && c2 < c)) { d = d2; c = c2; }
            }
            if (d < bestd || (d == bestd && c < besti)) { bestd = d; besti = c; }
        }
    }

    // ---- 4. finish: idx, gather e, exact ||x-e||^2, loss partial ----
    int idx = besti;
    if (lane == 0) out_idx[row] = (float)idx;
    const float4* e4 = (const float4*)(cb + (size_t)idx * DIM);
    const float4* x4 = (const float4*)(x + (size_t)row * DIM);
    float4* q4 = (float4*)(qout + (size_t)row * DIM);
    float s = 0.0f;
    #pragma unroll
    for (int u = 0; u < 2; ++u) {
        float4 e  = e4[lane + u * 64];
        float4 xv = x4[lane + u * 64];
        q4[lane + u * 64] = e;
        float dx = xv.x - e.x, dy = xv.y - e.y, dz = xv.z - e.z, dw = xv.w - e.w;
        s += dx * dx + dy * dy + dz * dz + dw * dw;
    }
    #pragma unroll
    for (int o = 32; o > 0; o >>= 1) s += __shfl_down(s, o);
    if (lane == 0) { sred[wave] = s; out_mind[row] = s; }
    __syncthreads();
    if (threadIdx.x == 0)
        lpart[blockIdx.x] = sred[0] + sred[1] + sred[2] + sred[3];
}

// ===========================================================================
// Kernel 4: final loss. loss_vq == loss_commit numerically => loss = 1.25*commit
__global__ __launch_bounds__(256) void loss_kernel(const float* __restrict__ lpart,
                                                   float* __restrict__ out_loss,
                                                   float* __restrict__ out_commit) {
    __shared__ float sm[256];
    float s = 0.0f;
    for (int i = threadIdx.x; i < 2048; i += 256) s += lpart[i];
    sm[threadIdx.x] = s;
    __syncthreads();
    #pragma unroll
    for (int o = 128; o > 0; o >>= 1) {
        if (threadIdx.x < o) sm[threadIdx.x] += sm[threadIdx.x + o];
        __syncthreads();
    }
    if (threadIdx.x == 0) {
        *out_commit = sm[0];
        *out_loss   = 1.25f * sm[0];
    }
}

// ===========================================================================
extern "C" void kernel_launch(void* const* d_in, const int* in_sizes, int n_in,
                              void* d_out, int out_size, void* d_ws, size_t ws_size,
                              hipStream_t stream) {
    const float* x  = (const float*)d_in[0];
    const float* cb = (const float*)d_in[1];
    float* out = (float*)d_out;
    float* ws  = (float*)d_ws;

    // A-hi staged in the quantized-output region (rewritten by refine_kernel)
    ushort_t* ahi    = (ushort_t*)d_out;
    ushort_t* bhi    = (ushort_t*)(ws + WS_BHI);
    ushort_t* minmat = (ushort_t*)(ws + WS_MINMAT);
    float* xnorm = ws + WS_XNORM;
    float* enorm = ws + WS_ENORM;
    float* enmax = ws + WS_ENMAX;
    float* lpart = ws + WS_LPART;

    conv_kernel<<<4096, 256, 0, stream>>>(x, cb, ahi, bhi, xnorm, enorm);
    prep_kernel<<<1, 256, 0, stream>>>(enorm, enmax);
    vq_mfma_kernel<<<2048, 256, 0, stream>>>(ahi, bhi, enorm, minmat);
    refine_kernel<<<2048, 256, 0, stream>>>(x, cb, xnorm, enorm, enmax, minmat,
                                            out + OUT_IDX, out + OUT_Q,
                                            out + OUT_MIND, lpart);
    loss_kernel<<<1, 256, 0, stream>>>(lpart, out + OUT_LOSS, out + OUT_COMMIT);
}

// Round 6
// 229.057 us; speedup vs baseline: 1.7274x; 1.7274x over previous
//
#include <hip/hip_runtime.h>

typedef __attribute__((ext_vector_type(8)))  short short8;   // 8 bf16 (4 VGPRs)
typedef __attribute__((ext_vector_type(16))) float f32x16;   // 32x32 MFMA acc
typedef unsigned short ushort_t;
typedef unsigned int uint32;
typedef unsigned long long uint64;

#define NROWS 8192
#define NCODE 8192
#define DIM   512

// error window: |(d'+xn) - D| <= 2*2.004*2^-8*sqrt(xn*enmax)  (bf16 RNE + C-S)
// W = 2x that + guard (covers fp32 epilogue rounding)
#define W_COEF  0.032f
#define W_GUARD 0.6f

// ---------------- d_out layout (floats) ----------------
#define OUT_Q      0
#define OUT_LOSS   4194304
#define OUT_IDX    4194305
#define OUT_MIND   4202497
#define OUT_COMMIT 4210689
// masks[8192][64][2] u64 live in d_out floats [2097152, 4194304) between
// vq (write) and refine (read); finish overwrites with qout afterwards.

// ---------------- ws layout (floats) ----------------
#define WS_ENORM  0           // 8192
#define WS_XNORM  8192        // 8192
#define WS_ENMAX  16384       // 1
#define WS_LPART  16448       // 2048
#define WS_MINS   32768       // mins[8192][64] f32 = 524288 floats
#define WS_BHI    557056      // 4,194,304 ushorts (8.39 MB)

// ===========================================================================
__device__ inline uint32 bf16_rne(float f) {
    uint32 u = __float_as_uint(f);
    return (u + 0x7FFFu + ((u >> 16) & 1u)) >> 16;
}

__device__ inline void gload16(const ushort_t* g, ushort_t* l) {
    __builtin_amdgcn_global_load_lds(
        (const __attribute__((address_space(1))) void*)g,
        (__attribute__((address_space(3))) void*)l, 16, 0, 0);
}

// ===========================================================================
// Kernel 1: convert x and codebook to fragment-ordered bf16 HI tiles only.
// Tile = 128 rows x 32 k, 8 KB, 8 chunks of 1 KB: chunk c = r32*2 + k16;
// lane L holds row = r32*32 + (L&31), k = k16*16 + (L>>5)*8 + j.
// Also exact fp32 row norms (xnorm for inputs, enorm for codebook).
__global__ __launch_bounds__(256) void conv_kernel(const float* __restrict__ x,
                                                   const float* __restrict__ cb,
                                                   ushort_t* __restrict__ ahi,
                                                   ushort_t* __restrict__ bhi,
                                                   float* __restrict__ xnorm,
                                                   float* __restrict__ enorm) {
    int gid  = blockIdx.x * 256 + threadIdx.x;   // 0..1048575
    bool isA = gid < 524288;
    int g    = isA ? gid : gid - 524288;
    int row  = g >> 6;
    int lane = g & 63;
    int k0   = lane * 8;
    const float* src = (isA ? x : cb) + (size_t)row * DIM + k0;
    float v[8];
    *(float4*)&v[0] = *(const float4*)src;
    *(float4*)&v[4] = *(const float4*)(src + 4);
    float s = 0.0f;
    uint32 h[8];
    #pragma unroll
    for (int i = 0; i < 8; ++i) {
        s += v[i] * v[i];
        h[i] = bf16_rne(v[i]);
    }
    int tile = (row >> 7) * 16 + (k0 >> 5);
    int rp = row & 127, kp = k0 & 31;
    int c  = (rp >> 5) * 2 + (kp >> 4);
    int L  = (rp & 31) + (((kp >> 3) & 1) << 5);
    size_t off = (size_t)tile * 4096 + c * 512 + L * 8;   // ushort units
    uint4 ph;
    ph.x = h[0] | (h[1] << 16); ph.y = h[2] | (h[3] << 16);
    ph.z = h[4] | (h[5] << 16); ph.w = h[6] | (h[7] << 16);
    if (isA) *(uint4*)(ahi + off) = ph;
    else     *(uint4*)(bhi + off) = ph;
    #pragma unroll
    for (int o = 32; o > 0; o >>= 1) s += __shfl_down(s, o);
    if (lane == 0) { if (isA) xnorm[row] = s; else enorm[row] = s; }
}

// ===========================================================================
// Kernel 1b: en_max = max over codebook norms (for the prune bound).
__global__ __launch_bounds__(256) void prep_kernel(const float* __restrict__ enorm,
                                                   float* __restrict__ enmax) {
    __shared__ float sm[256];
    float m = 0.0f;
    for (int i = threadIdx.x; i < NCODE; i += 256) m = fmaxf(m, enorm[i]);
    sm[threadIdx.x] = m;
    __syncthreads();
    #pragma unroll
    for (int o = 128; o > 0; o >>= 1) {
        if (threadIdx.x < o) sm[threadIdx.x] = fmaxf(sm[threadIdx.x], sm[threadIdx.x + o]);
        __syncthreads();
    }
    if (threadIdx.x == 0) enmax[0] = sm[0];
}

// ===========================================================================
// Kernel 2 (R6): hi-only GEMM, B-only LDS + A-direct global->reg.
// Block 256 rows x 128 cols, 4 waves stacked by row (wave tile 64x128,
// acc[2][4]). Per k16-step: B staged 4 KB (1 gload_lds/thread, double-buf
// 8 KB LDS), A read direct as fragment-ordered dwordx4 (R4-proven path;
// XCD-swizzled so each XCD's 1 MB A-band is L2-resident). 8 MFMA per
// staged KB (vs 2.7 in R5). Single epilogue: per row x 128-col slice emit
// f32 slice-min + 128-bit ballot mask of cols with d' <= lmin + W.
// Grid 2048 = 32 bx x 64 by; 2 blocks/CU.
__global__ __launch_bounds__(256, 2) void vq_mfma_kernel(
        const ushort_t* __restrict__ ahi, const ushort_t* __restrict__ bhi,
        const float* __restrict__ xnorm, const float* __restrict__ enorm,
        const float* __restrict__ enmax,
        float* __restrict__ mins, uint64* __restrict__ masks) {
    __shared__ __align__(16) ushort_t smem[4096];    // 2 x 4 KB B buffers

    const int tid  = threadIdx.x;            // 0..255
    const int wave = tid >> 6, lane = tid & 63;
    const int l31  = lane & 31, half = lane >> 5;
    const int q  = blockIdx.x;
    const int bx = (q & 7) * 4 + (q >> 9);   // 0..31 (256-row block), XCD=q&7
    const int by = (q >> 3) & 63;            // 0..63 (128-col slice)
    const int wr = wave;                     // 0..3 (64-row group)
    const int l8 = lane * 8;

    f32x16 acc[2][4];
    #pragma unroll
    for (int i = 0; i < 2; ++i)
        #pragma unroll
        for (int j = 0; j < 4; ++j)
            #pragma unroll
            for (int r = 0; r < 16; ++r) acc[i][j][r] = 0.0f;

    // A fragment offset in conv layout (rt = 32-row tile, kk = k16 index)
    auto FOFF = [&](int rt, int kk) -> size_t {
        return ((size_t)((rt >> 2) * 16 + (kk >> 1))) * 4096
             + (size_t)(((rt & 3) * 2 + (kk & 1)) * 512) + l8;
    };

    // stage B k16-step nn into buffer nn&1 (4 KB, 1 gload16/thread)
    auto stageB = [&](int nn) {
        const int kc = nn >> 1, k16 = nn & 1;
        ushort_t* S = smem + (nn & 1) * 2048;
        const size_t base = (((size_t)(by * 16 + kc)) << 12)
                          + ((tid >> 6) * 2 + k16) * 512 + (tid & 63) * 8;
        gload16(bhi + base, S + tid * 8);
    };

    short8 aA0, aA1, aB0, aB1;               // A frag double buffer
    auto loadA = [&](short8& f0, short8& f1, int nn) {
        f0 = *(const short8*)&ahi[FOFF(bx * 8 + wr * 2,     nn)];
        f1 = *(const short8*)&ahi[FOFF(bx * 8 + wr * 2 + 1, nn)];
    };

#define BODY(nn, A0, A1, N0, N1) do {                                         \
    __syncthreads();                      /* B(nn) in LDS, A(nn) in regs */   \
    if ((nn) + 1 < 32) { stageB((nn) + 1); loadA(N0, N1, (nn) + 1); }         \
    const ushort_t* S = smem + ((nn) & 1) * 2048;                             \
    short8 bh0 = *(const short8*)&S[0 * 512 + l8];                            \
    short8 bh1 = *(const short8*)&S[1 * 512 + l8];                            \
    short8 bh2 = *(const short8*)&S[2 * 512 + l8];                            \
    short8 bh3 = *(const short8*)&S[3 * 512 + l8];                            \
    __builtin_amdgcn_s_setprio(1);                                            \
    acc[0][0] = __builtin_amdgcn_mfma_f32_32x32x16_bf16(A0, bh0, acc[0][0], 0, 0, 0); \
    acc[0][1] = __builtin_amdgcn_mfma_f32_32x32x16_bf16(A0, bh1, acc[0][1], 0, 0, 0); \
    acc[0][2] = __builtin_amdgcn_mfma_f32_32x32x16_bf16(A0, bh2, acc[0][2], 0, 0, 0); \
    acc[0][3] = __builtin_amdgcn_mfma_f32_32x32x16_bf16(A0, bh3, acc[0][3], 0, 0, 0); \
    acc[1][0] = __builtin_amdgcn_mfma_f32_32x32x16_bf16(A1, bh0, acc[1][0], 0, 0, 0); \
    acc[1][1] = __builtin_amdgcn_mfma_f32_32x32x16_bf16(A1, bh1, acc[1][1], 0, 0, 0); \
    acc[1][2] = __builtin_amdgcn_mfma_f32_32x32x16_bf16(A1, bh2, acc[1][2], 0, 0, 0); \
    acc[1][3] = __builtin_amdgcn_mfma_f32_32x32x16_bf16(A1, bh3, acc[1][3], 0, 0, 0); \
    __builtin_amdgcn_s_setprio(0);                                            \
} while (0)

    stageB(0);
    loadA(aA0, aA1, 0);
    for (int n = 0; n < 32; n += 2) {
        BODY(n,     aA0, aA1, aB0, aB1);
        BODY(n + 1, aB0, aB1, aA0, aA1);
    }
#undef BODY

    // ---- epilogue: per row emit f32 slice-min + 128-bit candidate mask ----
    const float enm = enmax[0];
    float en[4];
    #pragma unroll
    for (int tj = 0; tj < 4; ++tj) en[tj] = enorm[by * 128 + tj * 32 + l31];

    #pragma unroll
    for (int ti = 0; ti < 2; ++ti)
        #pragma unroll
        for (int r = 0; r < 16; ++r) {
            const int row = bx * 256 + wr * 64 + ti * 32
                          + (r & 3) + 8 * (r >> 2) + 4 * half;
            const float xn = xnorm[row];
            const float W  = W_COEF * sqrtf(xn * enm) + W_GUARD;
            const float d0 = en[0] - 2.0f * acc[ti][0][r];
            const float d1 = en[1] - 2.0f * acc[ti][1][r];
            const float d2 = en[2] - 2.0f * acc[ti][2][r];
            const float d3 = en[3] - 2.0f * acc[ti][3][r];
            float m = fminf(fminf(d0, d1), fminf(d2, d3));
            #pragma unroll
            for (int o = 1; o < 32; o <<= 1) m = fminf(m, __shfl_xor(m, o));
            const float t = m + W;
            const uint64 b0 = __ballot(d0 <= t);
            const uint64 b1 = __ballot(d1 <= t);
            const uint64 b2 = __ballot(d2 <= t);
            const uint64 b3 = __ballot(d3 <= t);
            if (l31 == 0) {
                const int sh = half * 32;
                const uint64 m0 = ((b0 >> sh) & 0xFFFFFFFFull)
                                | (((b1 >> sh) & 0xFFFFFFFFull) << 32);
                const uint64 m1 = ((b2 >> sh) & 0xFFFFFFFFull)
                                | (((b3 >> sh) & 0xFFFFFFFFull) << 32);
                const size_t rec = (size_t)row * 64 + by;
                mins[rec] = m;
                masks[rec * 2]     = m0;
                masks[rec * 2 + 1] = m1;
            }
        }
}

// ===========================================================================
// Kernel 3 (R6): per-row argmin. Read 64 slice mins -> gmin; window
// thr = gmin + W; iterate candidate COLUMNS from the ballot masks
// (~3-8 per row), exact fp32 wave-coop distance for each. Write idx only.
__global__ __launch_bounds__(256) void refine_kernel(
        const float* __restrict__ x, const float* __restrict__ cb,
        const float* __restrict__ xnorm, const float* __restrict__ enorm,
        const float* __restrict__ enmax, const float* __restrict__ mins,
        const uint64* __restrict__ masks, float* __restrict__ out_idx) {
    const int wave = threadIdx.x >> 6, lane = threadIdx.x & 63;
    const int row  = blockIdx.x * 4 + wave;

    const float4* x4 = (const float4*)(x + (size_t)row * DIM);
    const float4 xa = x4[lane], xb = x4[lane + 64];
    const float  xn = xnorm[row];

    float m = (lane < 64) ? mins[(size_t)row * 64 + lane] : 3.4e38f;
    float gmin = m;
    #pragma unroll
    for (int o = 1; o < 64; o <<= 1) gmin = fminf(gmin, __shfl_xor(gmin, o));
    const float thr = gmin + W_COEF * sqrtf(xn * enmax[0]) + W_GUARD;

    uint64 qual = __ballot(m <= thr);
    float bestd = 3.4e38f;
    int   besti = 0x7FFFFFFF;

    auto eval = [&](int c) {
        const float4* e4 = (const float4*)(cb + (size_t)c * DIM);
        const float4 ea = e4[lane], eb = e4[lane + 64];
        float dot = xa.x * ea.x + xa.y * ea.y + xa.z * ea.z + xa.w * ea.w
                  + xb.x * eb.x + xb.y * eb.y + xb.z * eb.z + xb.w * eb.w;
        #pragma unroll
        for (int o = 1; o < 64; o <<= 1) dot += __shfl_xor(dot, o);
        const float D = xn + enorm[c] - 2.0f * dot;
        if (D < bestd || (D == bestd && c < besti)) { bestd = D; besti = c; }
    };

    while (qual) {
        const int s = __builtin_ctzll(qual); qual &= qual - 1;
        const uint64* mp = masks + ((size_t)row * 64 + s) * 2;
        uint64 mm0 = mp[0], mm1 = mp[1];
        const int cb0 = s * 128;
        while (mm0) { int b = __builtin_ctzll(mm0); mm0 &= mm0 - 1; eval(cb0 + b); }
        while (mm1) { int b = __builtin_ctzll(mm1); mm1 &= mm1 - 1; eval(cb0 + 64 + b); }
    }
    if (lane == 0) out_idx[row] = (float)besti;
}

// ===========================================================================
// Kernel 4: gather codebook row -> qout, exact fp32 ||x-e||^2 -> mind + loss
// partials. One 64-lane group per row. (Overwrites the masks region.)
__global__ __launch_bounds__(256) void finish_kernel(const float* __restrict__ x,
                                                     const float* __restrict__ cb,
                                                     const float* __restrict__ out_idx,
                                                     float* __restrict__ qout,
                                                     float* __restrict__ out_mind,
                                                     float* __restrict__ lpart) {
    __shared__ float sred[4];
    int row  = blockIdx.x * 4 + (threadIdx.x >> 6);
    int lane = threadIdx.x & 63;
    int idx  = (int)out_idx[row];

    const float4* e4 = (const float4*)(cb + (size_t)idx * DIM);
    const float4* x4 = (const float4*)(x + (size_t)row * DIM);
    float4* q4 = (float4*)(qout + (size_t)row * DIM);
    float s = 0.0f;
    #pragma unroll
    for (int u = 0; u < 2; ++u) {
        float4 e  = e4[lane + u * 64];
        float4 xv = x4[lane + u * 64];
        q4[lane + u * 64] = e;
        float dx = xv.x - e.x, dy = xv.y - e.y, dz = xv.z - e.z, dw = xv.w - e.w;
        s += dx * dx + dy * dy + dz * dz + dw * dw;
    }
    #pragma unroll
    for (int o = 32; o > 0; o >>= 1) s += __shfl_down(s, o);
    if (lane == 0) { sred[threadIdx.x >> 6] = s; out_mind[row] = s; }
    __syncthreads();
    if (threadIdx.x == 0)
        lpart[blockIdx.x] = sred[0] + sred[1] + sred[2] + sred[3];
}

// ===========================================================================
// Kernel 5: final loss. loss_vq == loss_commit numerically => loss = 1.25*commit
__global__ __launch_bounds__(256) void loss_kernel(const float* __restrict__ lpart,
                                                   float* __restrict__ out_loss,
                                                   float* __restrict__ out_commit) {
    __shared__ float sm[256];
    float s = 0.0f;
    for (int i = threadIdx.x; i < 2048; i += 256) s += lpart[i];
    sm[threadIdx.x] = s;
    __syncthreads();
    #pragma unroll
    for (int o = 128; o > 0; o >>= 1) {
        if (threadIdx.x < o) sm[threadIdx.x] += sm[threadIdx.x + o];
        __syncthreads();
    }
    if (threadIdx.x == 0) {
        *out_commit = sm[0];
        *out_loss   = 1.25f * sm[0];
    }
}

// ===========================================================================
extern "C" void kernel_launch(void* const* d_in, const int* in_sizes, int n_in,
                              void* d_out, int out_size, void* d_ws, size_t ws_size,
                              hipStream_t stream) {
    const float* x  = (const float*)d_in[0];
    const float* cb = (const float*)d_in[1];
    float* out = (float*)d_out;
    float* ws  = (float*)d_ws;

    // ahi in d_out 1st half; masks in d_out 2nd half (both dead before finish)
    ushort_t* ahi   = (ushort_t*)d_out;
    uint64*   masks = (uint64*)(out + 2097152);
    ushort_t* bhi   = (ushort_t*)(ws + WS_BHI);
    float* xnorm = ws + WS_XNORM;
    float* enorm = ws + WS_ENORM;
    float* enmax = ws + WS_ENMAX;
    float* mins  = ws + WS_MINS;
    float* lpart = ws + WS_LPART;

    conv_kernel<<<4096, 256, 0, stream>>>(x, cb, ahi, bhi, xnorm, enorm);
    prep_kernel<<<1, 256, 0, stream>>>(enorm, enmax);
    vq_mfma_kernel<<<2048, 256, 0, stream>>>(ahi, bhi, xnorm, enorm, enmax,
                                             mins, masks);
    refine_kernel<<<2048, 256, 0, stream>>>(x, cb, xnorm, enorm, enmax,
                                            mins, masks, out + OUT_IDX);
    finish_kernel<<<2048, 256, 0, stream>>>(x, cb, out + OUT_IDX, out + OUT_Q,
                                            out + OUT_MIND, lpart);
    loss_kernel<<<1, 256, 0, stream>>>(lpart, out + OUT_LOSS, out + OUT_COMMIT);
}